// Round 1
// baseline (3405.753 us; speedup 1.0000x reference)
//
#include <hip/hip_runtime.h>
#include <math.h>

#define B_SZ   1024
#define SEQ    17      // S+1
#define KV     16      // S
#define HDIM   256
#define NHEAD  8
#define DH     32
#define INF    150
#define OUTD   22
#define LN_EPS 1e-5f
#define N1     (B_SZ * SEQ)    // 17408 groups in block 0

struct Smem {
    float x[SEQ][HDIM];     // token features (post input-GEMM or loaded)
    float kp[KV][HDIM];
    float vp[KV][HDIM];
    float qp[HDIM];
    float att[NHEAD][KV];
    float obuf[HDIM];
    float hl[HDIM];
    float red[4];
    int   ids[SEQ];
    float rows[SEQ][INF];   // gathered node_feats rows (kernel 1 only)
};

__device__ __forceinline__ float block_sum256(float v, float* red) {
    // wave (64-lane) reduce, then combine 4 waves via LDS
    #pragma unroll
    for (int off = 32; off > 0; off >>= 1) v += __shfl_down(v, off);
    int wid = threadIdx.x >> 6, lane = threadIdx.x & 63;
    __syncthreads();               // protect red from any previous use
    if (lane == 0) red[wid] = v;
    __syncthreads();
    return red[0] + red[1] + red[2] + red[3];
}

__device__ __forceinline__ float layer_norm_val(float v, const float* g, const float* b,
                                                Smem& sm) {
    float s = block_sum256(v, sm.red);
    float m = s * (1.f / HDIM);
    float d = v - m;
    float s2 = block_sum256(d * d, sm.red);
    float r = rsqrtf(s2 * (1.f / HDIM) + LN_EPS);
    return d * r * g[threadIdx.x] + b[threadIdx.x];
}

// Runs one attention block for one group. sm.x[0..16][*] must be populated.
// Writes the 256-wide output row to outrow.
__device__ void attn_block(Smem& sm, int l,
                           const float* Wqkv, const float* bqkv,
                           const float* Wo, const float* bo,
                           const float* Wf, const float* bf,
                           const float* ln_g, const float* ln_b,
                           float* outrow) {
    const int tid = threadIdx.x;
    const float* Wq = Wqkv + (size_t)(l * 3 + 0) * HDIM * HDIM;
    const float* Wk = Wqkv + (size_t)(l * 3 + 1) * HDIM * HDIM;
    const float* Wv = Wqkv + (size_t)(l * 3 + 2) * HDIM * HDIM;
    const float* bq = bqkv + (l * 3 + 0) * HDIM;
    const float* bk = bqkv + (l * 3 + 1) * HDIM;
    const float* bv = bqkv + (l * 3 + 2) * HDIM;

    // ---- q projection (thread c owns column c) ----
    {
        const int c = tid;
        float acc = 0.f;
        for (int k = 0; k < HDIM; k++) acc += sm.x[0][k] * Wq[k * HDIM + c];
        sm.qp[c] = acc + bq[c];
    }
    // ---- k/v projections: 16 tokens, weight read amortized over tokens ----
    {
        const int c = tid;
        float acck[KV], accv[KV];
        #pragma unroll
        for (int s = 0; s < KV; s++) { acck[s] = 0.f; accv[s] = 0.f; }
        for (int k = 0; k < HDIM; k++) {
            float wk = Wk[k * HDIM + c];
            float wv = Wv[k * HDIM + c];
            #pragma unroll
            for (int s = 0; s < KV; s++) {
                float xv = sm.x[s + 1][k];
                acck[s] += xv * wk;
                accv[s] += xv * wv;
            }
        }
        float bbk = bk[c], bbv = bv[c];
        #pragma unroll
        for (int s = 0; s < KV; s++) {
            sm.kp[s][c] = acck[s] + bbk;
            sm.vp[s][c] = accv[s] + bbv;
        }
    }
    __syncthreads();

    // ---- attention logits: 8 heads x 16 keys ----
    if (tid < NHEAD * KV) {
        int h = tid / KV, k = tid % KV;
        float s = 0.f;
        #pragma unroll
        for (int d = 0; d < DH; d++) s += sm.qp[h * DH + d] * sm.kp[k][h * DH + d];
        sm.att[h][k] = s * 0.17677669529663687f;   // 1/sqrt(32)
    }
    __syncthreads();
    // ---- softmax over 16 keys per head ----
    if (tid < NHEAD) {
        int h = tid;
        float m = -1e30f;
        #pragma unroll
        for (int k = 0; k < KV; k++) m = fmaxf(m, sm.att[h][k]);
        float sum = 0.f;
        #pragma unroll
        for (int k = 0; k < KV; k++) { float e = __expf(sm.att[h][k] - m); sm.att[h][k] = e; sum += e; }
        float inv = 1.f / sum;
        #pragma unroll
        for (int k = 0; k < KV; k++) sm.att[h][k] *= inv;
    }
    __syncthreads();
    // ---- o = att @ vp ----
    {
        const int c = tid;
        const int h = c / DH;
        float o = 0.f;
        #pragma unroll
        for (int k = 0; k < KV; k++) o += sm.att[h][k] * sm.vp[k][c];
        sm.obuf[c] = o;
    }
    __syncthreads();
    // ---- output projection + residual with raw q ----
    float hval;
    {
        const int c = tid;
        const float* Wol = Wo + (size_t)l * HDIM * HDIM;
        float acc = 0.f;
        for (int k = 0; k < HDIM; k++) acc += sm.obuf[k] * Wol[k * HDIM + c];
        hval = acc + bo[l * HDIM + c] + sm.x[0][c];
    }
    // ---- LN 1 ----
    hval = layer_norm_val(hval, ln_g + (2 * l) * HDIM, ln_b + (2 * l) * HDIM, sm);
    sm.hl[tid] = hval;
    __syncthreads();
    // ---- FF + residual ----
    {
        const int c = tid;
        const float* Wfl = Wf + (size_t)l * HDIM * HDIM;
        float acc = 0.f;
        for (int k = 0; k < HDIM; k++) acc += sm.hl[k] * Wfl[k * HDIM + c];
        hval = hval + acc + bf[l * HDIM + c];
    }
    // ---- LN 2 ----
    hval = layer_norm_val(hval, ln_g + (2 * l + 1) * HDIM, ln_b + (2 * l + 1) * HDIM, sm);
    outrow[tid] = hval;
}

// Block 0: fused gather + input GEMM + attention. One workgroup per group n.
__global__ __launch_bounds__(256) void k_block1(
    const float* __restrict__ nf, const int* __restrict__ batch,
    const int* __restrict__ nbr2, const int* __restrict__ nbr1,
    const float* __restrict__ W_in, const float* __restrict__ b_in,
    const float* __restrict__ Wqkv, const float* __restrict__ bqkv,
    const float* __restrict__ Wo, const float* __restrict__ bo,
    const float* __restrict__ Wf, const float* __restrict__ bf,
    const float* __restrict__ ln_g, const float* __restrict__ ln_b,
    float* __restrict__ h1out) {
    __shared__ Smem sm;
    const int n = blockIdx.x;
    const int tid = threadIdx.x;

    // token ids for this group
    if (tid < SEQ) {
        int id;
        if (tid == 0) {
            int b = n / SEQ, s1 = n % SEQ;
            id = (s1 == 0) ? batch[b] : nbr2[b * KV + (s1 - 1)];
        } else {
            id = nbr1[n * KV + (tid - 1)];
        }
        sm.ids[tid] = id;
    }
    __syncthreads();

    // gather node_feats rows into LDS
    for (int idx = tid; idx < SEQ * INF; idx += 256) {
        int s = idx / INF, k = idx % INF;
        sm.rows[s][k] = nf[(size_t)sm.ids[s] * INF + k];
    }
    __syncthreads();

    // input GEMM + ReLU: x[s][c], thread c owns one column, 17 accumulators
    {
        const int c = tid;
        float acc[SEQ];
        #pragma unroll
        for (int s = 0; s < SEQ; s++) acc[s] = 0.f;
        for (int k = 0; k < INF; k++) {
            float w = W_in[k * HDIM + c];
            #pragma unroll
            for (int s = 0; s < SEQ; s++) acc[s] += sm.rows[s][k] * w;
        }
        float bb = b_in[c];
        #pragma unroll
        for (int s = 0; s < SEQ; s++) sm.x[s][c] = fmaxf(acc[s] + bb, 0.f);
    }
    __syncthreads();

    attn_block(sm, 0, Wqkv, bqkv, Wo, bo, Wf, bf, ln_g, ln_b, h1out + (size_t)n * HDIM);
}

// Block 1: load 17 rows of h1, run attention block l=1.
__global__ __launch_bounds__(256) void k_block2(
    const float* __restrict__ h1,
    const float* __restrict__ Wqkv, const float* __restrict__ bqkv,
    const float* __restrict__ Wo, const float* __restrict__ bo,
    const float* __restrict__ Wf, const float* __restrict__ bf,
    const float* __restrict__ ln_g, const float* __restrict__ ln_b,
    float* __restrict__ h2out) {
    __shared__ Smem sm;
    const int b = blockIdx.x;
    const int tid = threadIdx.x;
    #pragma unroll
    for (int s = 0; s < SEQ; s++)
        sm.x[s][tid] = h1[(size_t)(b * SEQ + s) * HDIM + tid];
    __syncthreads();
    attn_block(sm, 1, Wqkv, bqkv, Wo, bo, Wf, bf, ln_g, ln_b, h2out + (size_t)b * HDIM);
}

// Output head: logits + softmax over 22 classes. One 64-thread wave per batch row.
__global__ __launch_bounds__(64) void k_out(
    const float* __restrict__ h2, const float* __restrict__ W_out,
    const float* __restrict__ b_out, float* __restrict__ out) {
    const int b = blockIdx.x, j = threadIdx.x;
    __shared__ float xr[HDIM];
    for (int k = j; k < HDIM; k += 64) xr[k] = h2[(size_t)b * HDIM + k];
    __syncthreads();
    float logit = -1e30f;
    if (j < OUTD) {
        float acc = b_out[j];
        for (int k = 0; k < HDIM; k++) acc += xr[k] * W_out[k * OUTD + j];
        logit = acc;
    }
    float m = logit;
    #pragma unroll
    for (int off = 32; off > 0; off >>= 1) m = fmaxf(m, __shfl_xor(m, off));
    float e = (j < OUTD) ? __expf(logit - m) : 0.f;
    float s = e;
    #pragma unroll
    for (int off = 32; off > 0; off >>= 1) s += __shfl_xor(s, off);
    if (j < OUTD) out[(size_t)b * OUTD + j] = e / s;
}

extern "C" void kernel_launch(void* const* d_in, const int* in_sizes, int n_in,
                              void* d_out, int out_size, void* d_ws, size_t ws_size,
                              hipStream_t stream) {
    const float* nf    = (const float*)d_in[0];
    const int*   batch = (const int*)d_in[1];
    const int*   nbr2  = (const int*)d_in[2];
    const int*   nbr1  = (const int*)d_in[3];
    const float* W_in  = (const float*)d_in[4];
    const float* b_in  = (const float*)d_in[5];
    const float* Wqkv  = (const float*)d_in[6];
    const float* bqkv  = (const float*)d_in[7];
    const float* Wo    = (const float*)d_in[8];
    const float* bo    = (const float*)d_in[9];
    const float* Wf    = (const float*)d_in[10];
    const float* bf    = (const float*)d_in[11];
    const float* ln_g  = (const float*)d_in[12];
    const float* ln_b  = (const float*)d_in[13];
    const float* W_out = (const float*)d_in[14];
    const float* b_out = (const float*)d_in[15];
    float* out = (float*)d_out;

    float* h1 = (float*)d_ws;                                 // 17408*256 f32 = 17.8 MB
    float* h2 = h1 + (size_t)N1 * HDIM;                       // 1024*256 f32 = 1 MB

    hipLaunchKernelGGL(k_block1, dim3(N1), dim3(256), 0, stream,
                       nf, batch, nbr2, nbr1, W_in, b_in, Wqkv, bqkv,
                       Wo, bo, Wf, bf, ln_g, ln_b, h1);
    hipLaunchKernelGGL(k_block2, dim3(B_SZ), dim3(256), 0, stream,
                       h1, Wqkv, bqkv, Wo, bo, Wf, bf, ln_g, ln_b, h2);
    hipLaunchKernelGGL(k_out, dim3(B_SZ), dim3(64), 0, stream,
                       h2, W_out, b_out, out);
}

// Round 2
// 426.915 us; speedup vs baseline: 7.9776x; 7.9776x over previous
//
#include <hip/hip_runtime.h>
#include <hip/hip_bf16.h>
#include <math.h>

typedef unsigned short ushort_t;
typedef __bf16 bf16x8 __attribute__((ext_vector_type(8)));
typedef float  f32x4  __attribute__((ext_vector_type(4)));

#define B_SZ   1024
#define SEQ    17
#define KVN    16
#define HDIM   256
#define NHEAD  8
#define DH     32
#define INF    150
#define OUTD   22
#define LN_EPS 1e-5f
#define N1     (B_SZ * SEQ)      // 17408
#define NN_    100000

// ---------------- workspace layout (bytes, all 512-aligned) ----------------
constexpr size_t SZ_H0    = (size_t)NN_ * 256 * 2;        // 51,200,000
constexpr size_t SZ_KV0   = (size_t)NN_ * 512 * 2;        // 102,400,000
constexpr size_t SZ_ROW   = (size_t)N1 * 256 * 2;         // 8,912,896
constexpr size_t OFF_H0   = 0;
constexpr size_t OFF_KV0  = OFF_H0 + SZ_H0;
constexpr size_t OFF_QKV1 = OFF_KV0;                       // alias (KV0 dead after A0)
constexpr size_t OFF_O1   = OFF_QKV1 + (size_t)N1 * 768 * 2;
constexpr size_t OFF_HA2  = OFF_O1 + (size_t)B_SZ * 256 * 2;
constexpr size_t OFF_H2   = OFF_HA2 + (size_t)B_SZ * 256 * 2;
constexpr size_t OFF_Q0   = OFF_KV0 + SZ_KV0;
constexpr size_t OFF_O0   = OFF_Q0 + SZ_ROW;               // later aliased by h1
constexpr size_t OFF_H1   = OFF_O0;                        // alias (o0 dead after G3)
constexpr size_t OFF_HA   = OFF_O0 + SZ_ROW;
constexpr size_t OFF_IDS  = OFF_HA + SZ_ROW;               // 17408 * 4
constexpr size_t OFF_WTIN = OFF_IDS + (size_t)N1 * 4;      // 256*160*2
constexpr size_t OFF_WKV0 = OFF_WTIN + 256 * 160 * 2;      // 512*256*2
constexpr size_t OFF_WQ0  = OFF_WKV0 + 512 * 256 * 2;      // 256*256*2
constexpr size_t OFF_WKVQ1= OFF_WQ0 + 256 * 256 * 2;       // 768*256*2
constexpr size_t OFF_WO0  = OFF_WKVQ1 + 768 * 256 * 2;
constexpr size_t OFF_WF0  = OFF_WO0 + 256 * 256 * 2;
constexpr size_t OFF_WO1  = OFF_WF0 + 256 * 256 * 2;
constexpr size_t OFF_WF1  = OFF_WO1 + 256 * 256 * 2;
constexpr size_t OFF_B1   = OFF_WF1 + 256 * 256 * 2;       // 768 * 4

__device__ __forceinline__ ushort_t f2bfu(float x) {
    __hip_bfloat16 h = __float2bfloat16(x);
    return *reinterpret_cast<ushort_t*>(&h);
}
__device__ __forceinline__ float bfu2f(ushort_t u) {
    __hip_bfloat16 h;
    *reinterpret_cast<ushort_t*>(&h) = u;
    return __bfloat162float(h);
}
__device__ __forceinline__ f32x4 mfma16(bf16x8 a, bf16x8 b, f32x4 c) {
    return __builtin_amdgcn_mfma_f32_16x16x32_bf16(a, b, c, 0, 0, 0);
}

// ---------------- prep: weight transposes + bias permute + ids1 ----------------
// job y: 0..10 weight transposes (dst[n][k] = src[k][n], bf16, zero-pad k>=Kvalid)
//        11: ids1, 12: layer-1 qkv bias permute
__global__ __launch_bounds__(256) void k_prep(
    const float* __restrict__ W_in, const float* __restrict__ Wqkv,
    const float* __restrict__ Wo, const float* __restrict__ Wf,
    const float* __restrict__ bqkv,
    const int* __restrict__ batch, const int* __restrict__ nbr2,
    char* __restrict__ ws) {
    const int job = blockIdx.y;
    const int idx = blockIdx.x * 256 + threadIdx.x;
    if (job == 11) {
        if (idx < N1) {
            int b = idx / SEQ, s = idx % SEQ;
            ((int*)(ws + OFF_IDS))[idx] = (s == 0) ? batch[b] : nbr2[b * KVN + s - 1];
        }
        return;
    }
    if (job == 12) {
        if (idx < 768) ((float*)(ws + OFF_B1))[idx] = bqkv[768 + ((idx + 256) % 768)];
        return;
    }
    const float* src = nullptr; ushort_t* dst = nullptr;
    int Kpad = 256, Kvalid = 256;
    switch (job) {
        case 0:  src = W_in;           dst = (ushort_t*)(ws + OFF_WTIN); Kpad = 160; Kvalid = 150; break;
        case 1:  src = Wqkv + 65536;   dst = (ushort_t*)(ws + OFF_WKV0); break;            // Wk0
        case 2:  src = Wqkv + 131072;  dst = (ushort_t*)(ws + OFF_WKV0) + 65536; break;    // Wv0
        case 3:  src = Wqkv;           dst = (ushort_t*)(ws + OFF_WQ0); break;             // Wq0
        case 4:  src = Wqkv + 262144;  dst = (ushort_t*)(ws + OFF_WKVQ1); break;           // Wk1
        case 5:  src = Wqkv + 327680;  dst = (ushort_t*)(ws + OFF_WKVQ1) + 65536; break;   // Wv1
        case 6:  src = Wqkv + 196608;  dst = (ushort_t*)(ws + OFF_WKVQ1) + 131072; break;  // Wq1
        case 7:  src = Wo;             dst = (ushort_t*)(ws + OFF_WO0); break;
        case 8:  src = Wo + 65536;     dst = (ushort_t*)(ws + OFF_WO1); break;
        case 9:  src = Wf;             dst = (ushort_t*)(ws + OFF_WF0); break;
        case 10: src = Wf + 65536;     dst = (ushort_t*)(ws + OFF_WF1); break;
    }
    const int total = 256 * Kpad;
    if (idx >= total) return;
    int n = idx / Kpad, k = idx % Kpad;
    dst[idx] = (k < Kvalid) ? f2bfu(src[(size_t)k * 256 + n]) : (ushort_t)0;
}

// ---------------- generic 64x64 MFMA GEMM, bias(+relu) epilogue, bf16 out ------
// A: bf16 (or f32 when SRCF32) row-major [M][lda]; Bt: bf16 [N][ldb] (= B^T)
template<bool SRCF32, bool RELU>
__global__ __launch_bounds__(256) void gemm64(
    const void* __restrict__ Asrc, const ushort_t* __restrict__ Bt,
    const float* __restrict__ biasN, ushort_t* __restrict__ out,
    int M, int Ksteps, int kvalid, int lda, int ldb, int ldo,
    const int* __restrict__ arid) {
    __shared__ ushort_t Al[64][40];
    __shared__ ushort_t Bl[64][40];
    const int tid = threadIdx.x;
    const int m0 = blockIdx.x * 64, n0 = blockIdx.y * 64;
    const int lane = tid & 63, w = tid >> 6, wm = w >> 1, wn = w & 1;
    const int srow = tid >> 2, sch = tid & 3;

    f32x4 acc[2][2] = {};
    for (int s = 0; s < Ksteps; ++s) {
        const int kk = s * 32;
        // stage A
        {
            int gm = m0 + srow;
            bool valid = gm < M;
            if (arid) gm = valid ? arid[gm] : 0;
            if (SRCF32) {
                const float* A = (const float*)Asrc;
                ushort_t tmp[8];
                #pragma unroll
                for (int j = 0; j < 8; ++j) {
                    int k = kk + sch * 8 + j;
                    tmp[j] = (valid && k < kvalid) ? f2bfu(A[(size_t)gm * lda + k]) : (ushort_t)0;
                }
                *reinterpret_cast<int4*>(&Al[srow][sch * 8]) = *reinterpret_cast<int4*>(tmp);
            } else {
                const ushort_t* A = (const ushort_t*)Asrc;
                int4 v = {0, 0, 0, 0};
                if (valid) v = *reinterpret_cast<const int4*>(A + (size_t)gm * lda + kk + sch * 8);
                *reinterpret_cast<int4*>(&Al[srow][sch * 8]) = v;
            }
        }
        // stage B
        {
            int nrow = n0 + srow;
            int4 v = *reinterpret_cast<const int4*>(Bt + (size_t)nrow * ldb + kk + sch * 8);
            *reinterpret_cast<int4*>(&Bl[srow][sch * 8]) = v;
        }
        __syncthreads();
        const int lr = lane & 15, lk = (lane >> 4) * 8;
        bf16x8 a0 = *reinterpret_cast<const bf16x8*>(&Al[wm * 32 + lr][lk]);
        bf16x8 a1 = *reinterpret_cast<const bf16x8*>(&Al[wm * 32 + 16 + lr][lk]);
        bf16x8 b0 = *reinterpret_cast<const bf16x8*>(&Bl[wn * 32 + lr][lk]);
        bf16x8 b1 = *reinterpret_cast<const bf16x8*>(&Bl[wn * 32 + 16 + lr][lk]);
        acc[0][0] = mfma16(a0, b0, acc[0][0]);
        acc[0][1] = mfma16(a0, b1, acc[0][1]);
        acc[1][0] = mfma16(a1, b0, acc[1][0]);
        acc[1][1] = mfma16(a1, b1, acc[1][1]);
        __syncthreads();
    }
    // epilogue
    #pragma unroll
    for (int mi = 0; mi < 2; ++mi)
        #pragma unroll
        for (int ni = 0; ni < 2; ++ni)
            #pragma unroll
            for (int r = 0; r < 4; ++r) {
                int m = m0 + wm * 32 + mi * 16 + ((lane >> 4) << 2) + r;
                int n = n0 + wn * 32 + ni * 16 + (lane & 15);
                if (m < M) {
                    float v = acc[mi][ni][r] + biasN[n];
                    if (RELU) v = fmaxf(v, 0.f);
                    out[(size_t)m * ldo + n] = f2bfu(v);
                }
            }
}

// ---------------- 32x256 GEMM + bias + residual-gather + LayerNorm -------------
// out = LN( A@B + biasN + resmat[idx(row)] ) ; K=N=256 fixed
__global__ __launch_bounds__(256) void gemm_ln(
    const ushort_t* __restrict__ A, const ushort_t* __restrict__ Bt,
    const float* __restrict__ biasN,
    const ushort_t* __restrict__ resmat, const int* __restrict__ residx, int rstride,
    const float* __restrict__ lng, const float* __restrict__ lnb,
    ushort_t* __restrict__ out, int M) {
    __shared__ union {
        struct { ushort_t Al[32][40]; ushort_t Bl[256][40]; } s;
        struct { float xr[32][260]; float mrow[32]; float rrow[32]; int sidx[32]; } e;
    } sm;
    const int tid = threadIdx.x;
    const int m0 = blockIdx.x * 32;
    const int lane = tid & 63, w = tid >> 6;

    f32x4 acc[2][4] = {};
    for (int s = 0; s < 8; ++s) {
        const int kk = s * 32;
        if (tid < 128) {
            int row = tid >> 2, ch = tid & 3;
            *reinterpret_cast<int4*>(&sm.s.Al[row][ch * 8]) =
                *reinterpret_cast<const int4*>(A + (size_t)(m0 + row) * 256 + kk + ch * 8);
        }
        #pragma unroll
        for (int j = 0; j < 4; ++j)
            *reinterpret_cast<int4*>(&sm.s.Bl[tid][j * 8]) =
                *reinterpret_cast<const int4*>(Bt + (size_t)tid * 256 + kk + j * 8);
        __syncthreads();
        const int lr = lane & 15, lk = (lane >> 4) * 8;
        bf16x8 a0 = *reinterpret_cast<const bf16x8*>(&sm.s.Al[lr][lk]);
        bf16x8 a1 = *reinterpret_cast<const bf16x8*>(&sm.s.Al[16 + lr][lk]);
        #pragma unroll
        for (int ni = 0; ni < 4; ++ni) {
            bf16x8 b = *reinterpret_cast<const bf16x8*>(&sm.s.Bl[w * 64 + ni * 16 + lr][lk]);
            acc[0][ni] = mfma16(a0, b, acc[0][ni]);
            acc[1][ni] = mfma16(a1, b, acc[1][ni]);
        }
        __syncthreads();
    }
    // epilogue: acc -> LDS
    if (tid < 32) sm.e.sidx[tid] = residx ? residx[m0 + tid] : (m0 + tid) * rstride;
    #pragma unroll
    for (int mi = 0; mi < 2; ++mi)
        #pragma unroll
        for (int ni = 0; ni < 4; ++ni)
            #pragma unroll
            for (int r = 0; r < 4; ++r) {
                int rl = mi * 16 + ((lane >> 4) << 2) + r;
                int cl = w * 64 + ni * 16 + (lane & 15);
                sm.e.xr[rl][cl] = acc[mi][ni][r];
            }
    __syncthreads();
    { // bias + residual (column pass, coalesced residual reads)
        float bn = biasN[tid];
        for (int r = 0; r < 32; ++r)
            sm.e.xr[r][tid] += bn + bfu2f(resmat[(size_t)sm.e.sidx[r] * 256 + tid]);
    }
    __syncthreads();
    { // per-row mean/rstd: wave w handles rows 8w..8w+7
        for (int rr = w * 8; rr < w * 8 + 8; ++rr) {
            float4 v = *reinterpret_cast<const float4*>(&sm.e.xr[rr][lane * 4]);
            float s1 = v.x + v.y + v.z + v.w;
            float s2 = v.x * v.x + v.y * v.y + v.z * v.z + v.w * v.w;
            #pragma unroll
            for (int off = 32; off > 0; off >>= 1) {
                s1 += __shfl_xor(s1, off);
                s2 += __shfl_xor(s2, off);
            }
            if (lane == 0) {
                float m = s1 * (1.f / 256.f);
                float var = s2 * (1.f / 256.f) - m * m;
                sm.e.mrow[rr] = m;
                sm.e.rrow[rr] = rsqrtf(var + LN_EPS);
            }
        }
    }
    __syncthreads();
    {
        float g = lng[tid], b = lnb[tid];
        for (int r = 0; r < 32; ++r) {
            float v = (sm.e.xr[r][tid] - sm.e.mrow[r]) * sm.e.rrow[r] * g + b;
            out[(size_t)(m0 + r) * 256 + tid] = f2bfu(v);
        }
    }
}

// ---------------- attention core: gather pre-projected q/k/v, softmax, PV ------
__global__ __launch_bounds__(256) void attn_core(
    const ushort_t* __restrict__ q_all, int qld, int qoff, int qstride,
    const ushort_t* __restrict__ kv_all, int kvld, int koff, int voff,
    const int* __restrict__ kvidx, ushort_t* __restrict__ o_out) {
    __shared__ ushort_t Kl[KVN][264];
    __shared__ ushort_t Vl[KVN][264];
    __shared__ float qp[HDIM];
    __shared__ float att[NHEAD][17];
    __shared__ int kvi[KVN];
    const int g = blockIdx.x;
    const int tid = threadIdx.x;

    if (tid < KVN) kvi[tid] = kvidx ? kvidx[g * KVN + tid] : g * SEQ + 1 + tid;
    qp[tid] = bfu2f(q_all[(size_t)g * qstride * qld + qoff + tid]);
    __syncthreads();
    {
        int r = tid >> 4, seg = tid & 15;
        const ushort_t* kb = kv_all + (size_t)kvi[r] * kvld;
        *reinterpret_cast<int4*>(&Kl[r][seg * 16]) = *reinterpret_cast<const int4*>(kb + koff + seg * 16);
        *reinterpret_cast<int4*>(&Kl[r][seg * 16 + 8]) = *reinterpret_cast<const int4*>(kb + koff + seg * 16 + 8);
        *reinterpret_cast<int4*>(&Vl[r][seg * 16]) = *reinterpret_cast<const int4*>(kb + voff + seg * 16);
        *reinterpret_cast<int4*>(&Vl[r][seg * 16 + 8]) = *reinterpret_cast<const int4*>(kb + voff + seg * 16 + 8);
    }
    __syncthreads();
    if (tid < NHEAD * KVN) {
        int h = tid >> 4, k = tid & 15;
        float s = 0.f;
        #pragma unroll
        for (int d = 0; d < DH; ++d) s += qp[h * DH + d] * bfu2f(Kl[k][h * DH + d]);
        att[h][k] = s * 0.17677669529663687f;
    }
    __syncthreads();
    if (tid < NHEAD) {
        float m = -1e30f;
        #pragma unroll
        for (int k = 0; k < KVN; ++k) m = fmaxf(m, att[tid][k]);
        float sum = 0.f;
        #pragma unroll
        for (int k = 0; k < KVN; ++k) { float e = __expf(att[tid][k] - m); att[tid][k] = e; sum += e; }
        float inv = 1.f / sum;
        #pragma unroll
        for (int k = 0; k < KVN; ++k) att[tid][k] *= inv;
    }
    __syncthreads();
    {
        int h = tid >> 5;
        float o = 0.f;
        #pragma unroll
        for (int k = 0; k < KVN; ++k) o += att[h][k] * bfu2f(Vl[k][tid]);
        o_out[(size_t)g * 256 + tid] = f2bfu(o);
    }
}

// ---------------- output head ----------------
__global__ __launch_bounds__(64) void k_out(
    const ushort_t* __restrict__ h2, const float* __restrict__ W_out,
    const float* __restrict__ b_out, float* __restrict__ out) {
    const int b = blockIdx.x, j = threadIdx.x;
    __shared__ float xr[HDIM];
    for (int k = j; k < HDIM; k += 64) xr[k] = bfu2f(h2[(size_t)b * HDIM + k]);
    __syncthreads();
    float logit = -1e30f;
    if (j < OUTD) {
        float acc = b_out[j];
        for (int k = 0; k < HDIM; ++k) acc += xr[k] * W_out[k * OUTD + j];
        logit = acc;
    }
    float m = logit;
    #pragma unroll
    for (int off = 32; off > 0; off >>= 1) m = fmaxf(m, __shfl_xor(m, off));
    float e = (j < OUTD) ? __expf(logit - m) : 0.f;
    float s = e;
    #pragma unroll
    for (int off = 32; off > 0; off >>= 1) s += __shfl_xor(s, off);
    if (j < OUTD) out[(size_t)b * OUTD + j] = e / s;
}

extern "C" void kernel_launch(void* const* d_in, const int* in_sizes, int n_in,
                              void* d_out, int out_size, void* d_ws, size_t ws_size,
                              hipStream_t stream) {
    const float* nf    = (const float*)d_in[0];
    const int*   batch = (const int*)d_in[1];
    const int*   nbr2  = (const int*)d_in[2];
    const int*   nbr1  = (const int*)d_in[3];
    const float* W_in  = (const float*)d_in[4];
    const float* b_in  = (const float*)d_in[5];
    const float* Wqkv  = (const float*)d_in[6];
    const float* bqkv  = (const float*)d_in[7];
    const float* Wo    = (const float*)d_in[8];
    const float* bo    = (const float*)d_in[9];
    const float* Wf    = (const float*)d_in[10];
    const float* bf    = (const float*)d_in[11];
    const float* ln_g  = (const float*)d_in[12];
    const float* ln_b  = (const float*)d_in[13];
    const float* W_out = (const float*)d_in[14];
    const float* b_out = (const float*)d_in[15];
    float* out = (float*)d_out;
    char* ws = (char*)d_ws;

    ushort_t* h0   = (ushort_t*)(ws + OFF_H0);
    ushort_t* kv0  = (ushort_t*)(ws + OFF_KV0);
    ushort_t* q0   = (ushort_t*)(ws + OFF_Q0);
    ushort_t* o0   = (ushort_t*)(ws + OFF_O0);
    ushort_t* ha   = (ushort_t*)(ws + OFF_HA);
    ushort_t* h1   = (ushort_t*)(ws + OFF_H1);
    ushort_t* qkv1 = (ushort_t*)(ws + OFF_QKV1);
    ushort_t* o1   = (ushort_t*)(ws + OFF_O1);
    ushort_t* ha2  = (ushort_t*)(ws + OFF_HA2);
    ushort_t* h2   = (ushort_t*)(ws + OFF_H2);
    const int* ids1 = (const int*)(ws + OFF_IDS);

    // prep: 13 jobs
    hipLaunchKernelGGL(k_prep, dim3(256, 13), dim3(256), 0, stream,
                       W_in, Wqkv, Wo, Wf, bqkv, batch, nbr2, ws);
    // G1: h0_all = relu(nf @ W_in + b_in)   M=100000, K=150(pad160), N=256
    hipLaunchKernelGGL((gemm64<true, true>), dim3(1563, 4), dim3(256), 0, stream,
                       (const void*)nf, (const ushort_t*)(ws + OFF_WTIN), b_in, h0,
                       NN_, 5, 150, 150, 160, 256, (const int*)nullptr);
    // G2: KV0 = h0 @ [Wk0|Wv0] + [bk0|bv0]  M=100000, K=256, N=512
    hipLaunchKernelGGL((gemm64<false, false>), dim3(1563, 8), dim3(256), 0, stream,
                       (const void*)h0, (const ushort_t*)(ws + OFF_WKV0), bqkv + 256, kv0,
                       NN_, 8, 256, 256, 256, 512, (const int*)nullptr);
    // G2q: Q0 = h0[ids1] @ Wq0 + bq0        M=17408, K=256, N=256
    hipLaunchKernelGGL((gemm64<false, false>), dim3(272, 4), dim3(256), 0, stream,
                       (const void*)h0, (const ushort_t*)(ws + OFF_WQ0), bqkv, q0,
                       N1, 8, 256, 256, 256, 256, ids1);
    // A0: attention core, 17408 groups
    hipLaunchKernelGGL(attn_core, dim3(N1), dim3(256), 0, stream,
                       q0, 256, 0, 1, kv0, 512, 0, 256, nbr1, o0);
    // G3: ha = LN(o0 @ Wo0 + bo0 + h0[ids1])
    hipLaunchKernelGGL(gemm_ln, dim3(544), dim3(256), 0, stream,
                       o0, (const ushort_t*)(ws + OFF_WO0), bo,
                       h0, ids1, 1, ln_g, ln_b, ha, N1);
    // G4: h1 = LN(ha @ Wf0 + bf0 + ha)
    hipLaunchKernelGGL(gemm_ln, dim3(544), dim3(256), 0, stream,
                       ha, (const ushort_t*)(ws + OFF_WF0), bf,
                       ha, (const int*)nullptr, 1, ln_g + 256, ln_b + 256, h1, N1);
    // G5: QKV1 = h1 @ [Wk1|Wv1|Wq1] + b     M=17408, K=256, N=768
    hipLaunchKernelGGL((gemm64<false, false>), dim3(272, 12), dim3(256), 0, stream,
                       (const void*)h1, (const ushort_t*)(ws + OFF_WKVQ1),
                       (const float*)(ws + OFF_B1), qkv1,
                       N1, 8, 256, 256, 256, 768, (const int*)nullptr);
    // A1: attention core, 1024 groups (q = row 17g col 512+, kv = rows 17g+1+s)
    hipLaunchKernelGGL(attn_core, dim3(B_SZ), dim3(256), 0, stream,
                       qkv1, 768, 512, 17, qkv1, 768, 0, 256, (const int*)nullptr, o1);
    // G6: ha2 = LN(o1 @ Wo1 + bo1 + h1[17b])
    hipLaunchKernelGGL(gemm_ln, dim3(32), dim3(256), 0, stream,
                       o1, (const ushort_t*)(ws + OFF_WO1), bo + 256,
                       h1, (const int*)nullptr, 17, ln_g + 512, ln_b + 512, ha2, B_SZ);
    // G7: h2 = LN(ha2 @ Wf1 + bf1 + ha2)
    hipLaunchKernelGGL(gemm_ln, dim3(32), dim3(256), 0, stream,
                       ha2, (const ushort_t*)(ws + OFF_WF1), bf + 256,
                       ha2, (const int*)nullptr, 1, ln_g + 768, ln_b + 768, h2, B_SZ);
    // output head
    hipLaunchKernelGGL(k_out, dim3(B_SZ), dim3(64), 0, stream,
                       h2, W_out, b_out, out);
}

// Round 3
// 298.506 us; speedup vs baseline: 11.4093x; 1.4302x over previous
//
#include <hip/hip_runtime.h>
#include <hip/hip_bf16.h>
#include <math.h>

typedef unsigned short ushort_t;
typedef __bf16 bf16x8 __attribute__((ext_vector_type(8)));
typedef float  f32x4  __attribute__((ext_vector_type(4)));

#define B_SZ   1024
#define SEQ    17
#define KVN    16
#define HDIM   256
#define NHEAD  8
#define DH     32
#define INF    150
#define OUTD   22
#define LN_EPS 1e-5f
#define N1     (B_SZ * SEQ)      // 17408
#define NN_    100000

// ---------------- workspace layout (bytes, all 512-aligned) ----------------
constexpr size_t SZ_H0    = (size_t)NN_ * 256 * 2;        // 51,200,000
constexpr size_t SZ_KV0   = (size_t)NN_ * 512 * 2;        // 102,400,000
constexpr size_t SZ_ROW   = (size_t)N1 * 256 * 2;         // 8,912,896
constexpr size_t OFF_H0   = 0;
constexpr size_t OFF_KV0  = OFF_H0 + SZ_H0;
constexpr size_t OFF_QKV1 = OFF_KV0;                       // alias (KV0 dead after A0)
constexpr size_t OFF_O1   = OFF_QKV1 + (size_t)N1 * 768 * 2;
constexpr size_t OFF_HA2  = OFF_O1 + (size_t)B_SZ * 256 * 2;
constexpr size_t OFF_H2   = OFF_HA2 + (size_t)B_SZ * 256 * 2;
constexpr size_t OFF_Q0   = OFF_KV0 + SZ_KV0;
constexpr size_t OFF_O0   = OFF_Q0 + SZ_ROW;               // later aliased by h1
constexpr size_t OFF_H1   = OFF_O0;                        // alias (o0 dead after G3)
constexpr size_t OFF_HA   = OFF_O0 + SZ_ROW;
constexpr size_t OFF_IDS  = OFF_HA + SZ_ROW;               // 17408 * 4
constexpr size_t OFF_WTIN = OFF_IDS + (size_t)N1 * 4;      // 256*160*2
constexpr size_t OFF_WKV0 = OFF_WTIN + 256 * 160 * 2;      // 512*256*2
constexpr size_t OFF_WQ0  = OFF_WKV0 + 512 * 256 * 2;      // 256*256*2
constexpr size_t OFF_WKVQ1= OFF_WQ0 + 256 * 256 * 2;       // 768*256*2
constexpr size_t OFF_WO0  = OFF_WKVQ1 + 768 * 256 * 2;
constexpr size_t OFF_WF0  = OFF_WO0 + 256 * 256 * 2;
constexpr size_t OFF_WO1  = OFF_WF0 + 256 * 256 * 2;
constexpr size_t OFF_WF1  = OFF_WO1 + 256 * 256 * 2;
constexpr size_t OFF_B1   = OFF_WF1 + 256 * 256 * 2;       // 768 * 4

__device__ __forceinline__ ushort_t f2bfu(float x) {
    __hip_bfloat16 h = __float2bfloat16(x);
    return *reinterpret_cast<ushort_t*>(&h);
}
__device__ __forceinline__ float bfu2f(ushort_t u) {
    __hip_bfloat16 h;
    *reinterpret_cast<ushort_t*>(&h) = u;
    return __bfloat162float(h);
}
__device__ __forceinline__ f32x4 mfma16(bf16x8 a, bf16x8 b, f32x4 c) {
    return __builtin_amdgcn_mfma_f32_16x16x32_bf16(a, b, c, 0, 0, 0);
}

// ---------------- prep: weight transposes + bias permute + ids1 ----------------
__global__ __launch_bounds__(256) void k_prep(
    const float* __restrict__ W_in, const float* __restrict__ Wqkv,
    const float* __restrict__ Wo, const float* __restrict__ Wf,
    const float* __restrict__ bqkv,
    const int* __restrict__ batch, const int* __restrict__ nbr2,
    char* __restrict__ ws) {
    const int job = blockIdx.y;
    const int idx = blockIdx.x * 256 + threadIdx.x;
    if (job == 11) {
        if (idx < N1) {
            int b = idx / SEQ, s = idx % SEQ;
            ((int*)(ws + OFF_IDS))[idx] = (s == 0) ? batch[b] : nbr2[b * KVN + s - 1];
        }
        return;
    }
    if (job == 12) {
        if (idx < 768) ((float*)(ws + OFF_B1))[idx] = bqkv[768 + ((idx + 256) % 768)];
        return;
    }
    const float* src = nullptr; ushort_t* dst = nullptr;
    int Kpad = 256, Kvalid = 256;
    switch (job) {
        case 0:  src = W_in;           dst = (ushort_t*)(ws + OFF_WTIN); Kpad = 160; Kvalid = 150; break;
        case 1:  src = Wqkv + 65536;   dst = (ushort_t*)(ws + OFF_WKV0); break;            // Wk0
        case 2:  src = Wqkv + 131072;  dst = (ushort_t*)(ws + OFF_WKV0) + 65536; break;    // Wv0
        case 3:  src = Wqkv;           dst = (ushort_t*)(ws + OFF_WQ0); break;             // Wq0
        case 4:  src = Wqkv + 262144;  dst = (ushort_t*)(ws + OFF_WKVQ1); break;           // Wk1
        case 5:  src = Wqkv + 327680;  dst = (ushort_t*)(ws + OFF_WKVQ1) + 65536; break;   // Wv1
        case 6:  src = Wqkv + 196608;  dst = (ushort_t*)(ws + OFF_WKVQ1) + 131072; break;  // Wq1
        case 7:  src = Wo;             dst = (ushort_t*)(ws + OFF_WO0); break;
        case 8:  src = Wo + 65536;     dst = (ushort_t*)(ws + OFF_WO1); break;
        case 9:  src = Wf;             dst = (ushort_t*)(ws + OFF_WF0); break;
        case 10: src = Wf + 65536;     dst = (ushort_t*)(ws + OFF_WF1); break;
    }
    const int total = 256 * Kpad;
    if (idx >= total) return;
    int n = idx / Kpad, k = idx % Kpad;
    dst[idx] = (k < Kvalid) ? f2bfu(src[(size_t)k * 256 + n]) : (ushort_t)0;
}

// ============== fused: h0 = relu(nf@W_in+b), kv0 = h0@[Wk|Wv]+b ==============
// One block per 64-row M-tile. Phase 1 reads nf (f32) exactly once; phase 2
// consumes the h0 tile from LDS. h0 also written to global for Q0/residual.
__global__ __launch_bounds__(256, 2) void k_in_kv(
    const float* __restrict__ nf, const ushort_t* __restrict__ Wt_in,
    const float* __restrict__ b_in, const ushort_t* __restrict__ Wkv,
    const float* __restrict__ bqkv, ushort_t* __restrict__ h0,
    ushort_t* __restrict__ kv0) {
    __shared__ union {
        struct { ushort_t Ain[64][40]; ushort_t Bl[256][40]; } p1;  // 25.6 KB
        ushort_t Bl2[512][40];                                       // 41 KB
        ushort_t Sh[64][264];                                        // 33.8 KB
    } smu;
    __shared__ ushort_t Ah[64][264];                                 // 33.8 KB

    const int tid  = threadIdx.x;
    const int m0   = blockIdx.x * 64;
    const int lane = tid & 63, w = tid >> 6;
    const int lr = lane & 15, lk = (lane >> 4) * 8;
    const int rowA = tid >> 2, chA = tid & 3;

    // ---------------- phase 1: h0_tile = relu(A @ W_in + b_in) ----------------
    f32x4 acc1[4][4] = {};
    for (int s = 0; s < 5; ++s) {
        const int kk = s * 32;
        __syncthreads();
        { // stage A (f32 -> bf16)
            int gm = m0 + rowA;
            bool v = gm < NN_;
            int k0 = kk + chA * 8;
            ushort_t tmp[8];
            const float* ap = nf + (size_t)(v ? gm : 0) * INF + k0;
            if (v && k0 + 8 <= INF) {
                #pragma unroll
                for (int j = 0; j < 4; ++j) {
                    float2 f = *reinterpret_cast<const float2*>(ap + j * 2);
                    tmp[j * 2] = f2bfu(f.x); tmp[j * 2 + 1] = f2bfu(f.y);
                }
            } else {
                #pragma unroll
                for (int j = 0; j < 8; ++j)
                    tmp[j] = (v && k0 + j < INF) ? f2bfu(ap[j]) : (ushort_t)0;
            }
            *reinterpret_cast<int4*>(&smu.p1.Ain[rowA][chA * 8]) = *reinterpret_cast<int4*>(tmp);
        }
        { // stage B: Wt_in[256][160], k-slice
            const ushort_t* bp = Wt_in + (size_t)tid * 160 + kk;
            #pragma unroll
            for (int j = 0; j < 4; ++j)
                *reinterpret_cast<int4*>(&smu.p1.Bl[tid][j * 8]) =
                    *reinterpret_cast<const int4*>(bp + j * 8);
        }
        __syncthreads();
        bf16x8 a[4], b[4];
        #pragma unroll
        for (int mi = 0; mi < 4; ++mi)
            a[mi] = *reinterpret_cast<const bf16x8*>(&smu.p1.Ain[mi * 16 + lr][lk]);
        #pragma unroll
        for (int ni = 0; ni < 4; ++ni)
            b[ni] = *reinterpret_cast<const bf16x8*>(&smu.p1.Bl[w * 64 + ni * 16 + lr][lk]);
        #pragma unroll
        for (int mi = 0; mi < 4; ++mi)
            #pragma unroll
            for (int ni = 0; ni < 4; ++ni)
                acc1[mi][ni] = mfma16(a[mi], b[ni], acc1[mi][ni]);
    }
    // relu + bias -> Ah (bf16)
    __syncthreads();
    #pragma unroll
    for (int ni = 0; ni < 4; ++ni) {
        int col = w * 64 + ni * 16 + lr;
        float bb = b_in[col];
        #pragma unroll
        for (int mi = 0; mi < 4; ++mi)
            #pragma unroll
            for (int r = 0; r < 4; ++r) {
                int row = mi * 16 + (lane >> 4) * 4 + r;
                Ah[row][col] = f2bfu(fmaxf(acc1[mi][ni][r] + bb, 0.f));
            }
    }
    __syncthreads();
    // h0 tile -> global (coalesced)
    #pragma unroll
    for (int i = 0; i < 8; ++i) {
        int flat = tid + i * 256;            // 2048 chunks of 8 bf16
        int row = flat >> 5, c8 = (flat & 31) * 8;
        if (m0 + row < NN_)
            *reinterpret_cast<int4*>(h0 + (size_t)(m0 + row) * 256 + c8) =
                *reinterpret_cast<const int4*>(&Ah[row][c8]);
    }

    // ---------------- phase 2: kv_tile = h0_tile @ Wkv + b ----------------
    f32x4 acc2[4][8] = {};
    for (int s = 0; s < 8; ++s) {
        const int kk = s * 32;
        __syncthreads();
        { // stage B: Wkv[512][256], k-slice (2 rows per thread)
            #pragma unroll
            for (int rr = 0; rr < 2; ++rr) {
                int n = tid + rr * 256;
                const ushort_t* bp = Wkv + (size_t)n * 256 + kk;
                #pragma unroll
                for (int j = 0; j < 4; ++j)
                    *reinterpret_cast<int4*>(&smu.Bl2[n][j * 8]) =
                        *reinterpret_cast<const int4*>(bp + j * 8);
            }
        }
        __syncthreads();
        bf16x8 a[4], b[8];
        #pragma unroll
        for (int mi = 0; mi < 4; ++mi)
            a[mi] = *reinterpret_cast<const bf16x8*>(&Ah[mi * 16 + lr][kk + lk]);
        #pragma unroll
        for (int ni = 0; ni < 8; ++ni)
            b[ni] = *reinterpret_cast<const bf16x8*>(&smu.Bl2[w * 128 + ni * 16 + lr][lk]);
        #pragma unroll
        for (int mi = 0; mi < 4; ++mi)
            #pragma unroll
            for (int ni = 0; ni < 8; ++ni)
                acc2[mi][ni] = mfma16(a[mi], b[ni], acc2[mi][ni]);
    }
    // epilogue: bias, bf16, bounce through LDS for coalesced stores
    #pragma unroll
    for (int h = 0; h < 2; ++h) {
        __syncthreads();
        if ((w >> 1) == h) {
            int cb = (w & 1) * 128;
            #pragma unroll
            for (int ni = 0; ni < 8; ++ni) {
                int coll = cb + ni * 16 + lr;
                float bb = bqkv[256 + h * 256 + coll];
                #pragma unroll
                for (int mi = 0; mi < 4; ++mi)
                    #pragma unroll
                    for (int r = 0; r < 4; ++r) {
                        int row = mi * 16 + (lane >> 4) * 4 + r;
                        smu.Sh[row][coll] = f2bfu(acc2[mi][ni][r] + bb);
                    }
            }
        }
        __syncthreads();
        #pragma unroll
        for (int i = 0; i < 8; ++i) {
            int flat = tid + i * 256;
            int row = flat >> 5, c8 = (flat & 31) * 8;
            if (m0 + row < NN_)
                *reinterpret_cast<int4*>(kv0 + (size_t)(m0 + row) * 512 + h * 256 + c8) =
                    *reinterpret_cast<const int4*>(&smu.Sh[row][c8]);
        }
    }
}

// ---------------- generic 64x64 MFMA GEMM, bias epilogue, bf16 out ------
template<bool RELU>
__global__ __launch_bounds__(256) void gemm64(
    const ushort_t* __restrict__ Asrc, const ushort_t* __restrict__ Bt,
    const float* __restrict__ biasN, ushort_t* __restrict__ out,
    int M, int Ksteps, int lda, int ldb, int ldo,
    const int* __restrict__ arid) {
    __shared__ ushort_t Al[64][40];
    __shared__ ushort_t Bl[64][40];
    const int tid = threadIdx.x;
    const int m0 = blockIdx.x * 64, n0 = blockIdx.y * 64;
    const int lane = tid & 63, w = tid >> 6, wm = w >> 1, wn = w & 1;
    const int srow = tid >> 2, sch = tid & 3;

    f32x4 acc[2][2] = {};
    for (int s = 0; s < Ksteps; ++s) {
        const int kk = s * 32;
        {
            int gm = m0 + srow;
            bool valid = gm < M;
            if (arid) gm = valid ? arid[gm] : 0;
            int4 v = {0, 0, 0, 0};
            if (valid) v = *reinterpret_cast<const int4*>(Asrc + (size_t)gm * lda + kk + sch * 8);
            *reinterpret_cast<int4*>(&Al[srow][sch * 8]) = v;
        }
        {
            int nrow = n0 + srow;
            int4 v = *reinterpret_cast<const int4*>(Bt + (size_t)nrow * ldb + kk + sch * 8);
            *reinterpret_cast<int4*>(&Bl[srow][sch * 8]) = v;
        }
        __syncthreads();
        const int lr = lane & 15, lk = (lane >> 4) * 8;
        bf16x8 a0 = *reinterpret_cast<const bf16x8*>(&Al[wm * 32 + lr][lk]);
        bf16x8 a1 = *reinterpret_cast<const bf16x8*>(&Al[wm * 32 + 16 + lr][lk]);
        bf16x8 b0 = *reinterpret_cast<const bf16x8*>(&Bl[wn * 32 + lr][lk]);
        bf16x8 b1 = *reinterpret_cast<const bf16x8*>(&Bl[wn * 32 + 16 + lr][lk]);
        acc[0][0] = mfma16(a0, b0, acc[0][0]);
        acc[0][1] = mfma16(a0, b1, acc[0][1]);
        acc[1][0] = mfma16(a1, b0, acc[1][0]);
        acc[1][1] = mfma16(a1, b1, acc[1][1]);
        __syncthreads();
    }
    #pragma unroll
    for (int mi = 0; mi < 2; ++mi)
        #pragma unroll
        for (int ni = 0; ni < 2; ++ni)
            #pragma unroll
            for (int r = 0; r < 4; ++r) {
                int m = m0 + wm * 32 + mi * 16 + ((lane >> 4) << 2) + r;
                int n = n0 + wn * 32 + ni * 16 + (lane & 15);
                if (m < M) {
                    float v = acc[mi][ni][r] + biasN[n];
                    if (RELU) v = fmaxf(v, 0.f);
                    out[(size_t)m * ldo + n] = f2bfu(v);
                }
            }
}

// ---------------- 32x256 GEMM + bias + residual-gather + LayerNorm -------------
__global__ __launch_bounds__(256) void gemm_ln(
    const ushort_t* __restrict__ A, const ushort_t* __restrict__ Bt,
    const float* __restrict__ biasN,
    const ushort_t* __restrict__ resmat, const int* __restrict__ residx, int rstride,
    const float* __restrict__ lng, const float* __restrict__ lnb,
    ushort_t* __restrict__ out, int M) {
    __shared__ union {
        struct { ushort_t Al[32][40]; ushort_t Bl[256][40]; } s;
        struct { float xr[32][260]; float mrow[32]; float rrow[32]; int sidx[32]; } e;
    } sm;
    const int tid = threadIdx.x;
    const int m0 = blockIdx.x * 32;
    const int lane = tid & 63, w = tid >> 6;

    f32x4 acc[2][4] = {};
    for (int s = 0; s < 8; ++s) {
        const int kk = s * 32;
        if (tid < 128) {
            int row = tid >> 2, ch = tid & 3;
            *reinterpret_cast<int4*>(&sm.s.Al[row][ch * 8]) =
                *reinterpret_cast<const int4*>(A + (size_t)(m0 + row) * 256 + kk + ch * 8);
        }
        #pragma unroll
        for (int j = 0; j < 4; ++j)
            *reinterpret_cast<int4*>(&sm.s.Bl[tid][j * 8]) =
                *reinterpret_cast<const int4*>(Bt + (size_t)tid * 256 + kk + j * 8);
        __syncthreads();
        const int lr = lane & 15, lk = (lane >> 4) * 8;
        bf16x8 a0 = *reinterpret_cast<const bf16x8*>(&sm.s.Al[lr][lk]);
        bf16x8 a1 = *reinterpret_cast<const bf16x8*>(&sm.s.Al[16 + lr][lk]);
        #pragma unroll
        for (int ni = 0; ni < 4; ++ni) {
            bf16x8 b = *reinterpret_cast<const bf16x8*>(&sm.s.Bl[w * 64 + ni * 16 + lr][lk]);
            acc[0][ni] = mfma16(a0, b, acc[0][ni]);
            acc[1][ni] = mfma16(a1, b, acc[1][ni]);
        }
        __syncthreads();
    }
    if (tid < 32) sm.e.sidx[tid] = residx ? residx[m0 + tid] : (m0 + tid) * rstride;
    #pragma unroll
    for (int mi = 0; mi < 2; ++mi)
        #pragma unroll
        for (int ni = 0; ni < 4; ++ni)
            #pragma unroll
            for (int r = 0; r < 4; ++r) {
                int rl = mi * 16 + ((lane >> 4) << 2) + r;
                int cl = w * 64 + ni * 16 + (lane & 15);
                sm.e.xr[rl][cl] = acc[mi][ni][r];
            }
    __syncthreads();
    {
        float bn = biasN[tid];
        for (int r = 0; r < 32; ++r)
            sm.e.xr[r][tid] += bn + bfu2f(resmat[(size_t)sm.e.sidx[r] * 256 + tid]);
    }
    __syncthreads();
    {
        for (int rr = w * 8; rr < w * 8 + 8; ++rr) {
            float4 v = *reinterpret_cast<const float4*>(&sm.e.xr[rr][lane * 4]);
            float s1 = v.x + v.y + v.z + v.w;
            float s2 = v.x * v.x + v.y * v.y + v.z * v.z + v.w * v.w;
            #pragma unroll
            for (int off = 32; off > 0; off >>= 1) {
                s1 += __shfl_xor(s1, off);
                s2 += __shfl_xor(s2, off);
            }
            if (lane == 0) {
                float m = s1 * (1.f / 256.f);
                float var = s2 * (1.f / 256.f) - m * m;
                sm.e.mrow[rr] = m;
                sm.e.rrow[rr] = rsqrtf(var + LN_EPS);
            }
        }
    }
    __syncthreads();
    {
        float g = lng[tid], b = lnb[tid];
        for (int r = 0; r < 32; ++r) {
            float v = (sm.e.xr[r][tid] - sm.e.mrow[r]) * sm.e.rrow[r] * g + b;
            out[(size_t)(m0 + r) * 256 + tid] = f2bfu(v);
        }
    }
}

// ---------------- attention core ----------------
__global__ __launch_bounds__(256) void attn_core(
    const ushort_t* __restrict__ q_all, int qld, int qoff, int qstride,
    const ushort_t* __restrict__ kv_all, int kvld, int koff, int voff,
    const int* __restrict__ kvidx, ushort_t* __restrict__ o_out) {
    __shared__ ushort_t Kl[KVN][264];
    __shared__ ushort_t Vl[KVN][264];
    __shared__ float qp[HDIM];
    __shared__ float att[NHEAD][17];
    __shared__ int kvi[KVN];
    const int g = blockIdx.x;
    const int tid = threadIdx.x;

    if (tid < KVN) kvi[tid] = kvidx ? kvidx[g * KVN + tid] : g * SEQ + 1 + tid;
    qp[tid] = bfu2f(q_all[(size_t)g * qstride * qld + qoff + tid]);
    __syncthreads();
    {
        int r = tid >> 4, seg = tid & 15;
        const ushort_t* kb = kv_all + (size_t)kvi[r] * kvld;
        *reinterpret_cast<int4*>(&Kl[r][seg * 16]) = *reinterpret_cast<const int4*>(kb + koff + seg * 16);
        *reinterpret_cast<int4*>(&Kl[r][seg * 16 + 8]) = *reinterpret_cast<const int4*>(kb + koff + seg * 16 + 8);
        *reinterpret_cast<int4*>(&Vl[r][seg * 16]) = *reinterpret_cast<const int4*>(kb + voff + seg * 16);
        *reinterpret_cast<int4*>(&Vl[r][seg * 16 + 8]) = *reinterpret_cast<const int4*>(kb + voff + seg * 16 + 8);
    }
    __syncthreads();
    if (tid < NHEAD * KVN) {
        int h = tid >> 4, k = tid & 15;
        float s = 0.f;
        #pragma unroll
        for (int d = 0; d < DH; ++d) s += qp[h * DH + d] * bfu2f(Kl[k][h * DH + d]);
        att[h][k] = s * 0.17677669529663687f;
    }
    __syncthreads();
    if (tid < NHEAD) {
        float m = -1e30f;
        #pragma unroll
        for (int k = 0; k < KVN; ++k) m = fmaxf(m, att[tid][k]);
        float sum = 0.f;
        #pragma unroll
        for (int k = 0; k < KVN; ++k) { float e = __expf(att[tid][k] - m); att[tid][k] = e; sum += e; }
        float inv = 1.f / sum;
        #pragma unroll
        for (int k = 0; k < KVN; ++k) att[tid][k] *= inv;
    }
    __syncthreads();
    {
        int h = tid >> 5;
        float o = 0.f;
        #pragma unroll
        for (int k = 0; k < KVN; ++k) o += att[h][k] * bfu2f(Vl[k][tid]);
        o_out[(size_t)g * 256 + tid] = f2bfu(o);
    }
}

// ---------------- output head ----------------
__global__ __launch_bounds__(64) void k_out(
    const ushort_t* __restrict__ h2, const float* __restrict__ W_out,
    const float* __restrict__ b_out, float* __restrict__ out) {
    const int b = blockIdx.x, j = threadIdx.x;
    __shared__ float xr[HDIM];
    for (int k = j; k < HDIM; k += 64) xr[k] = bfu2f(h2[(size_t)b * HDIM + k]);
    __syncthreads();
    float logit = -1e30f;
    if (j < OUTD) {
        float acc = b_out[j];
        for (int k = 0; k < HDIM; ++k) acc += xr[k] * W_out[k * OUTD + j];
        logit = acc;
    }
    float m = logit;
    #pragma unroll
    for (int off = 32; off > 0; off >>= 1) m = fmaxf(m, __shfl_xor(m, off));
    float e = (j < OUTD) ? __expf(logit - m) : 0.f;
    float s = e;
    #pragma unroll
    for (int off = 32; off > 0; off >>= 1) s += __shfl_xor(s, off);
    if (j < OUTD) out[(size_t)b * OUTD + j] = e / s;
}

extern "C" void kernel_launch(void* const* d_in, const int* in_sizes, int n_in,
                              void* d_out, int out_size, void* d_ws, size_t ws_size,
                              hipStream_t stream) {
    const float* nf    = (const float*)d_in[0];
    const int*   batch = (const int*)d_in[1];
    const int*   nbr2  = (const int*)d_in[2];
    const int*   nbr1  = (const int*)d_in[3];
    const float* W_in  = (const float*)d_in[4];
    const float* b_in  = (const float*)d_in[5];
    const float* Wqkv  = (const float*)d_in[6];
    const float* bqkv  = (const float*)d_in[7];
    const float* Wo    = (const float*)d_in[8];
    const float* bo    = (const float*)d_in[9];
    const float* Wf    = (const float*)d_in[10];
    const float* bf    = (const float*)d_in[11];
    const float* ln_g  = (const float*)d_in[12];
    const float* ln_b  = (const float*)d_in[13];
    const float* W_out = (const float*)d_in[14];
    const float* b_out = (const float*)d_in[15];
    float* out = (float*)d_out;
    char* ws = (char*)d_ws;

    ushort_t* h0   = (ushort_t*)(ws + OFF_H0);
    ushort_t* kv0  = (ushort_t*)(ws + OFF_KV0);
    ushort_t* q0   = (ushort_t*)(ws + OFF_Q0);
    ushort_t* o0   = (ushort_t*)(ws + OFF_O0);
    ushort_t* ha   = (ushort_t*)(ws + OFF_HA);
    ushort_t* h1   = (ushort_t*)(ws + OFF_H1);
    ushort_t* qkv1 = (ushort_t*)(ws + OFF_QKV1);
    ushort_t* o1   = (ushort_t*)(ws + OFF_O1);
    ushort_t* ha2  = (ushort_t*)(ws + OFF_HA2);
    ushort_t* h2   = (ushort_t*)(ws + OFF_H2);
    const int* ids1 = (const int*)(ws + OFF_IDS);

    hipLaunchKernelGGL(k_prep, dim3(256, 13), dim3(256), 0, stream,
                       W_in, Wqkv, Wo, Wf, bqkv, batch, nbr2, ws);
    // fused G1+G2: h0 + kv0
    hipLaunchKernelGGL(k_in_kv, dim3(1563), dim3(256), 0, stream,
                       nf, (const ushort_t*)(ws + OFF_WTIN), b_in,
                       (const ushort_t*)(ws + OFF_WKV0), bqkv, h0, kv0);
    // Q0 = h0[ids1] @ Wq0 + bq0
    hipLaunchKernelGGL((gemm64<false>), dim3(272, 4), dim3(256), 0, stream,
                       h0, (const ushort_t*)(ws + OFF_WQ0), bqkv, q0,
                       N1, 8, 256, 256, 256, ids1);
    // A0
    hipLaunchKernelGGL(attn_core, dim3(N1), dim3(256), 0, stream,
                       q0, 256, 0, 1, kv0, 512, 0, 256, nbr1, o0);
    // G3: ha = LN(o0 @ Wo0 + bo0 + h0[ids1])
    hipLaunchKernelGGL(gemm_ln, dim3(544), dim3(256), 0, stream,
                       o0, (const ushort_t*)(ws + OFF_WO0), bo,
                       h0, ids1, 1, ln_g, ln_b, ha, N1);
    // G4: h1 = LN(ha @ Wf0 + bf0 + ha)
    hipLaunchKernelGGL(gemm_ln, dim3(544), dim3(256), 0, stream,
                       ha, (const ushort_t*)(ws + OFF_WF0), bf,
                       ha, (const int*)nullptr, 1, ln_g + 256, ln_b + 256, h1, N1);
    // G5: QKV1 = h1 @ [Wk1|Wv1|Wq1] + b
    hipLaunchKernelGGL((gemm64<false>), dim3(272, 12), dim3(256), 0, stream,
                       h1, (const ushort_t*)(ws + OFF_WKVQ1),
                       (const float*)(ws + OFF_B1), qkv1,
                       N1, 8, 256, 256, 768, (const int*)nullptr);
    // A1
    hipLaunchKernelGGL(attn_core, dim3(B_SZ), dim3(256), 0, stream,
                       qkv1, 768, 512, 17, qkv1, 768, 0, 256, (const int*)nullptr, o1);
    // G6: ha2 = LN(o1 @ Wo1 + bo1 + h1[17b])
    hipLaunchKernelGGL(gemm_ln, dim3(32), dim3(256), 0, stream,
                       o1, (const ushort_t*)(ws + OFF_WO1), bo + 256,
                       h1, (const int*)nullptr, 17, ln_g + 512, ln_b + 512, ha2, B_SZ);
    // G7: h2 = LN(ha2 @ Wf1 + bf1 + ha2)
    hipLaunchKernelGGL(gemm_ln, dim3(32), dim3(256), 0, stream,
                       ha2, (const ushort_t*)(ws + OFF_WF1), bf + 256,
                       ha2, (const int*)nullptr, 1, ln_g + 768, ln_b + 768, h2, B_SZ);
    hipLaunchKernelGGL(k_out, dim3(B_SZ), dim3(64), 0, stream,
                       h2, W_out, b_out, out);
}